// Round 2
// baseline (543.578 us; speedup 1.0000x reference)
//
#include <hip/hip_runtime.h>
#include <cstdint>

#define S 2048
#define D 64
#define QT 16                  // q rows per block (full 16x16 MFMA rows)
#define EPAD 8
#define ESTRIDE (S + EPAD)     // shorts; 2056*2 = 4112 B row stride (16B-divisible)

typedef __attribute__((ext_vector_type(8))) short short8;
typedef __attribute__((ext_vector_type(4))) short short4v;
typedef __attribute__((ext_vector_type(4))) float floatx4;

static __device__ __forceinline__ unsigned short f2bf(float f) {
    union { float f; uint32_t u; } v; v.f = f;
    uint32_t r = (v.u + 0x7fffu + ((v.u >> 16) & 1u)) >> 16;   // RNE
    return (unsigned short)r;
}
static __device__ __forceinline__ float bf2f(unsigned short s) {
    union { uint32_t u; float f; } v; v.u = ((uint32_t)s) << 16;
    return v.f;
}

// ---- pre-pass 1: flat fp32 -> bf16 (for K) ----
__global__ void convert_bf16_kernel(const float* __restrict__ in,
                                    unsigned short* __restrict__ out, int n8) {
    int i = (blockIdx.x * 256 + threadIdx.x);
    if (i >= n8) return;
    const float* p = in + (size_t)i * 8;
    short8 o;
    #pragma unroll
    for (int j = 0; j < 8; ++j) o[j] = (short)f2bf(p[j]);
    *(short8*)(out + (size_t)i * 8) = o;
}

// ---- pre-pass 2: V [BH][S][D] fp32 -> Vt [BH][D][S] bf16 ----
__global__ void transpose_v_kernel(const float* __restrict__ v,
                                   unsigned short* __restrict__ vt) {
    __shared__ unsigned short tile[64][72];
    const int tid = threadIdx.x;
    const int bh = blockIdx.x >> 5;        // S/64 = 32 tiles per bh
    const int s0 = (blockIdx.x & 31) * 64;
    #pragma unroll
    for (int rep = 0; rep < 16; ++rep) {
        int idx = rep * 256 + tid;
        int sl = idx >> 6, d = idx & 63;
        tile[sl][d] = f2bf(v[((size_t)bh * S + s0 + sl) * D + d]);
    }
    __syncthreads();
    #pragma unroll
    for (int rep = 0; rep < 16; ++rep) {
        int idx = rep * 256 + tid;
        int d = idx >> 6, sl = idx & 63;
        vt[((size_t)bh * D + d) * S + s0 + sl] = tile[sl][d];
    }
}

// Swapped-operand attention (C: row=k idx, col=q row) with explicit
// register-rotated prefetch (depth 4) on the bias/K streams and the V stream.
template <bool PRE>
__global__ __launch_bounds__(512, 4)
void attn_kernel(const float* __restrict__ q,
                 const float* __restrict__ k,
                 const float* __restrict__ v,
                 const float* __restrict__ bias,
                 const unsigned short* __restrict__ kb16,  // [BH][S][D] bf16
                 const unsigned short* __restrict__ vt16,  // [BH][D][S] bf16
                 float* __restrict__ gout,   // [BH][S][D]
                 float* __restrict__ wout)   // [BH][S][S]
{
    __shared__ __align__(16) unsigned short Elds[QT][ESTRIDE];
    __shared__ __align__(16) float pacc[QT][D];   // PV partials from k-half 1
    __shared__ float rowsum[QT];

    const int tid  = threadIdx.x;
    const int wv   = tid >> 6;      // 0..7
    const int lane = tid & 63;
    const int quad = lane >> 4;
    const int l16  = lane & 15;

    const int bh = blockIdx.x >> 7;        // / (S/QT) = /128
    const int qt = blockIdx.x & 127;
    const int q0 = qt * QT;

    if (tid < QT) rowsum[tid] = 0.0f;
    __syncthreads();

    // ---- Q fragment (B operand): lane l16 -> q row q0+l16, elems quad*8+j (+s*32) ----
    short8 bq[2];
    {
        const float* qrow = q + ((size_t)bh * S + q0 + l16) * D;
        #pragma unroll
        for (int s = 0; s < 2; ++s) {
            const float* p = qrow + s * 32 + quad * 8;
            #pragma unroll
            for (int j = 0; j < 8; ++j) bq[s][j] = (short)f2bf(p[j]);
        }
    }

    const float* brow = bias + ((size_t)bh * S + q0 + l16) * S;

    // ---- QK^T + gaussian bias + exp; wave wv handles keys t*128 + wv*16 ----
    float psum = 0.0f;
    if (PRE) {
        const unsigned short* kbase = kb16 + ((size_t)bh * S + l16) * D + quad * 8;
        floatx4 bb[4];
        short8 ak0[4], ak1[4];
        #pragma unroll
        for (int p = 0; p < 4; ++p) {
            const int kb = p * 128 + wv * 16;
            const unsigned short* kr = kbase + (size_t)kb * D;
            ak0[p] = *(const short8*)kr;
            ak1[p] = *(const short8*)(kr + 32);
            bb[p]  = *(const floatx4*)(brow + kb + quad * 4);
        }
        // one QK step: compute tile TT from slot u, optionally prefetch TT+4 into slot u
        #define QK_STEP(u, TT, PF) { \
            const int kb_ = (TT) * 128 + wv * 16; \
            floatx4 c = {0.f, 0.f, 0.f, 0.f}; \
            c = __builtin_amdgcn_mfma_f32_16x16x32_bf16(ak0[u], bq[0], c, 0, 0, 0); \
            c = __builtin_amdgcn_mfma_f32_16x16x32_bf16(ak1[u], bq[1], c, 0, 0, 0); \
            const floatx4 bqd = bb[u]; \
            if (PF) { \
                const int kb2_ = kb_ + 512; \
                const unsigned short* kr_ = kbase + (size_t)kb2_ * D; \
                ak0[u] = *(const short8*)kr_; \
                ak1[u] = *(const short8*)(kr_ + 32); \
                bb[u]  = *(const floatx4*)(brow + kb2_ + quad * 4); \
            } \
            short4v ev; \
            _Pragma("unroll") \
            for (int r = 0; r < 4; ++r) { \
                const float logit = c[r] * 0.125f - 0.5f * bqd[r] * bqd[r]; \
                const float e = __expf(logit); \
                psum += e; \
                ev[r] = (short)f2bf(e); \
            } \
            *(short4v*)&Elds[l16][kb_ + quad * 4] = ev; \
        }
        for (int t = 0; t < 12; t += 4) {
            QK_STEP(0, t + 0, 1)
            QK_STEP(1, t + 1, 1)
            QK_STEP(2, t + 2, 1)
            QK_STEP(3, t + 3, 1)
        }
        QK_STEP(0, 12, 0)
        QK_STEP(1, 13, 0)
        QK_STEP(2, 14, 0)
        QK_STEP(3, 15, 0)
        #undef QK_STEP
    } else {
        for (int t = 0; t < 16; ++t) {
            const int kb = t * 128 + wv * 16;
            short8 ak[2];
            const float* krow = k + ((size_t)bh * S + kb + l16) * D;
            #pragma unroll
            for (int s = 0; s < 2; ++s) {
                const float* p = krow + s * 32 + quad * 8;
                #pragma unroll
                for (int j = 0; j < 8; ++j) ak[s][j] = (short)f2bf(p[j]);
            }
            floatx4 c = {0.f, 0.f, 0.f, 0.f};
            c = __builtin_amdgcn_mfma_f32_16x16x32_bf16(ak[0], bq[0], c, 0, 0, 0);
            c = __builtin_amdgcn_mfma_f32_16x16x32_bf16(ak[1], bq[1], c, 0, 0, 0);
            const floatx4 b4 = *(const floatx4*)(brow + kb + quad * 4);
            short4v ev;
            #pragma unroll
            for (int r = 0; r < 4; ++r) {
                const float logit = c[r] * 0.125f - 0.5f * b4[r] * b4[r];
                const float e = __expf(logit);
                psum += e;
                ev[r] = (short)f2bf(e);
            }
            *(short4v*)&Elds[l16][kb + quad * 4] = ev;
        }
    }
    // rowsum for q-row l16: reduce across the 4 quads, then cross-wave atomic
    psum += __shfl_xor(psum, 16);
    psum += __shfl_xor(psum, 32);
    if (lane < 16) atomicAdd(&rowsum[l16], psum);

    __syncthreads();

    // ---- write normalized weights: 32 threads per row, b128 LDS reads, 32B/thread stores ----
    {
        const int r = tid >> 5;          // 0..15
        const int l = tid & 31;
        const float rinv = 1.0f / rowsum[r];
        float* wrow = wout + ((size_t)bh * S + q0 + r) * S;
        #pragma unroll 2
        for (int it = 0; it < 8; ++it) {
            const int col = it * 256 + l * 8;
            short8 ev8 = *(const short8*)&Elds[r][col];
            floatx4 o0, o1;
            #pragma unroll
            for (int j = 0; j < 4; ++j) o0[j] = bf2f((unsigned short)ev8[j]) * rinv;
            #pragma unroll
            for (int j = 0; j < 4; ++j) o1[j] = bf2f((unsigned short)ev8[j + 4]) * rinv;
            *(floatx4*)(wrow + col) = o0;
            *(floatx4*)(wrow + col + 4) = o1;
        }
    }

    // ---- PV: wave wv -> dim tile (wv&3)*16, k-half (wv>>2) ----
    {
        const int dt = wv & 3;
        const int kh = wv >> 2;
        const int dimc = dt * 16 + l16;
        floatx4 acc0 = {0.f, 0.f, 0.f, 0.f};
        floatx4 acc1 = {0.f, 0.f, 0.f, 0.f};
        if (PRE) {
            const unsigned short* vrow = vt16 + ((size_t)bh * D + dimc) * S
                                       + kh * 1024 + quad * 8;
            const unsigned short* erow = &Elds[l16][kh * 1024 + quad * 8];
            short8 vv[4];
            #pragma unroll
            for (int p = 0; p < 4; ++p) vv[p] = *(const short8*)(vrow + p * 32);
            #define PV_STEP(u, SL, PF, ACC) { \
                short8 af = *(const short8*)(erow + (SL) * 32); \
                ACC = __builtin_amdgcn_mfma_f32_16x16x32_bf16(af, vv[u], ACC, 0, 0, 0); \
                if (PF) vv[u] = *(const short8*)(vrow + ((SL) + 4) * 32); \
            }
            for (int sl = 0; sl < 28; sl += 4) {
                PV_STEP(0, sl + 0, 1, acc0)
                PV_STEP(1, sl + 1, 1, acc1)
                PV_STEP(2, sl + 2, 1, acc0)
                PV_STEP(3, sl + 3, 1, acc1)
            }
            PV_STEP(0, 28, 0, acc0)
            PV_STEP(1, 29, 0, acc1)
            PV_STEP(2, 30, 0, acc0)
            PV_STEP(3, 31, 0, acc1)
            #undef PV_STEP
        } else {
            const float* vcol = v + (size_t)bh * S * D + dimc;
            for (int sl = 0; sl < 32; ++sl) {
                const int sb = kh * 1024 + sl * 32 + quad * 8;
                short8 af = *(const short8*)&Elds[l16][sb];
                short8 bfv;
                #pragma unroll
                for (int j = 0; j < 8; ++j)
                    bfv[j] = (short)f2bf(vcol[(size_t)(sb + j) * D]);
                acc0 = __builtin_amdgcn_mfma_f32_16x16x32_bf16(af, bfv, acc0, 0, 0, 0);
            }
        }
        floatx4 acc = acc0 + acc1;
        // C layout: row(m) = q row = quad*4+r, col(n) = dim = dimc
        if (kh == 1) {
            #pragma unroll
            for (int r = 0; r < 4; ++r) pacc[quad * 4 + r][dimc] = acc[r];
        }
        __syncthreads();
        if (kh == 0) {
            #pragma unroll
            for (int r = 0; r < 4; ++r) {
                const int row = quad * 4 + r;
                const float rinv = 1.0f / rowsum[row];
                gout[((size_t)bh * S + q0 + row) * D + dimc] =
                    (acc[r] + pacc[row][dimc]) * rinv;
            }
        }
    }
}

extern "C" void kernel_launch(void* const* d_in, const int* in_sizes, int n_in,
                              void* d_out, int out_size, void* d_ws, size_t ws_size,
                              hipStream_t stream) {
    const float* q    = (const float*)d_in[0];
    const float* k    = (const float*)d_in[1];
    const float* v    = (const float*)d_in[2];
    const float* bias = (const float*)d_in[3];
    const int BH = in_sizes[0] / (S * D);          // 16
    float* gout = (float*)d_out;
    float* wout = gout + (size_t)BH * S * D;

    const size_t nkv = (size_t)BH * S * D;         // 2,097,152 elements
    const bool pre = ws_size >= nkv * 2 * sizeof(unsigned short);

    dim3 grid(BH * (S / QT));                      // 2048 blocks

    if (pre) {
        unsigned short* kb16 = (unsigned short*)d_ws;
        unsigned short* vt16 = kb16 + nkv;
        int n8 = (int)(nkv / 8);
        convert_bf16_kernel<<<(n8 + 255) / 256, 256, 0, stream>>>(k, kb16, n8);
        transpose_v_kernel<<<BH * (S / 64), 256, 0, stream>>>(v, vt16);
        attn_kernel<true><<<grid, dim3(512), 0, stream>>>(q, k, v, bias, kb16, vt16, gout, wout);
    } else {
        attn_kernel<false><<<grid, dim3(512), 0, stream>>>(q, k, v, bias, nullptr, nullptr, gout, wout);
    }
}